// Round 6
// baseline (56996.051 us; speedup 1.0000x reference)
//
#include <hip/hip_runtime.h>
#include <hip/hip_cooperative_groups.h>

namespace cg = cooperative_groups;

#define Bb 256
#define Tt 512
#define Dd 512
#define Hh 512
#define KTOT 1024
#define FOURH 2048
#define GWGS 64   // WGs per row-group

typedef __attribute__((ext_vector_type(8))) short bf16x8;
typedef __attribute__((ext_vector_type(4))) float f32x4;

__device__ __forceinline__ unsigned short f2bf(float f) {
    union { float f; unsigned u; } x; x.f = f;
    unsigned u = x.u;
    unsigned r = u + 0x7FFFu + ((u >> 16) & 1u);
    return (unsigned short)(r >> 16);
}
__device__ __forceinline__ float bf2f(unsigned short s) {
    union { unsigned u; float f; } x; x.u = ((unsigned)s) << 16;
    return x.f;
}

// Transpose + split W = [Wx; Wh] (K=1024 rows, N=2048 cols) into
// WT_hi/WT_lo layout [N=2048][K=1024] bf16 (k-contiguous per output column).
__global__ void prep_w(const float* __restrict__ Wx, const float* __restrict__ Wh,
                       unsigned short* __restrict__ WT_hi, unsigned short* __restrict__ WT_lo) {
    __shared__ float tile[32][33];
    int n0 = (blockIdx.x & 63) * 32;
    int k0 = (blockIdx.x >> 6) * 32;
    int tx = threadIdx.x & 31;
    int ty = threadIdx.x >> 5;
    for (int q = 0; q < 4; ++q) {
        int k = k0 + ty + q * 8;
        int n = n0 + tx;
        float v = (k < Dd) ? Wx[(size_t)k * FOURH + n] : Wh[(size_t)(k - Dd) * FOURH + n];
        tile[ty + q * 8][tx] = v;
    }
    __syncthreads();
    for (int q = 0; q < 4; ++q) {
        int nl = ty + q * 8;
        int kl = tx;
        float v = tile[kl][nl];
        unsigned short hi = f2bf(v);
        unsigned short lo = f2bf(v - bf2f(hi));
        size_t o = (size_t)(n0 + nl) * KTOT + (size_t)(k0 + kl);
        WT_hi[o] = hi;
        WT_lo[o] = lo;
    }
}

__global__ void init_state(float* __restrict__ c_st,
                           unsigned short* __restrict__ h_bufs,
                           unsigned int* __restrict__ cnt) {
    int i = blockIdx.x * blockDim.x + threadIdx.x;
    if (i < Bb * Hh) {
        c_st[i] = 0.f;
        for (int q = 0; q < 4; ++q)
            h_bufs[(size_t)q * Bb * Hh + i] = 0;
    }
    if (i < 256) cnt[i] = 0u;
}

// ---------------- Persistent kernel, ROW-GROUP partitioned ------------------
// 256 WGs x 512 thr. group = bx&3 owns rows 64g..64g+63 (all 2048 gate-cols
// spread over the group's 64 WGs). cidx = bx>>2 owns h-cols j0=8*cidx..+7
// (gate cols g*512 + j0..j0+7 for all 4 gates = 32 gate-cols).
// 8 waves: rt = w8>>1 (row-subtile of 16), cw = w8&1 (16 of the 32 gate-cols).
// h is group-local: written and read only by this group's WGs ->
// per-step barrier is a GROUP-LOCAL 64-WG atomic barrier, not grid-wide.
// h double-buffered; c in registers; split-3 bf16 MFMA (independent chains).
__global__ __launch_bounds__(512) void lstm_persist2(
    const float* __restrict__ X, const int* __restrict__ lengths,
    const unsigned short* __restrict__ WT_hi, const unsigned short* __restrict__ WT_lo,
    const float* __restrict__ bias,
    unsigned short* __restrict__ h_base,
    unsigned int* __restrict__ cnt,
    float* __restrict__ out)
{
    __shared__ float zbuf[64][33];

    const int bx = blockIdx.x;
    const int group = bx & 3;
    const int cidx = bx >> 2;          // 0..63
    const int r0 = group * 64;
    const int j0 = cidx * 8;
    const int tid = threadIdx.x;
    const int w8 = tid >> 6;
    const int lane = tid & 63;
    const int rt = w8 >> 1;            // 0..3
    const int cw = w8 & 1;             // 0..1
    const int l15 = lane & 15;

    const size_t HB = (size_t)Bb * Hh;
    unsigned short* h_hi0 = h_base;
    unsigned short* h_lo0 = h_base + HB;
    unsigned short* h_hi1 = h_base + 2 * HB;
    unsigned short* h_lo1 = h_base + 3 * HB;

    // B operand: column (gate, h-col) for this lane
    const int gsel = cw * 2 + (l15 >> 3);          // gate 0..3
    const int colg = gsel * 512 + j0 + (l15 & 7);  // 0..2047
    const size_t bbase = (size_t)colg * KTOT;
    const int klo = (lane >> 4) * 8;               // 0,8,16,24
    const unsigned short* bhp = &WT_hi[bbase];
    const unsigned short* blp = &WT_lo[bbase];

    // A operand: this lane's row
    const int rowA = r0 + rt * 16 + l15;
    const float* xrow = &X[(size_t)rowA * Tt * Dd];
    const size_t hoff = (size_t)rowA * Hh;

    // epilogue ownership: 1 h-element per thread (64 rows x 8 h-cols = 512)
    const int er = tid >> 3;            // 0..63
    const int ej = tid & 7;             // 0..7
    const int row_g = r0 + er;
    const int col_h = j0 + ej;
    const size_t oidx = (size_t)row_g * Hh + col_h;
    int oT = lengths[row_g] - 1; if (oT < 0) oT = 0;
    const float b0 = bias[col_h], b1 = bias[512 + col_h],
                b2 = bias[1024 + col_h], b3 = bias[1536 + col_h];
    float creg = 0.f;

    unsigned int* mycnt = &cnt[group * 32];   // 128B-padded counters

    for (int t = 0; t < Tt; ++t) {
        const unsigned short* hrh = (t & 1) ? h_hi1 : h_hi0;
        const unsigned short* hrl = (t & 1) ? h_lo1 : h_lo0;
        unsigned short* hwh = (t & 1) ? h_hi0 : h_hi1;
        unsigned short* hwl = (t & 1) ? h_lo0 : h_lo1;

        f32x4 ahh = (f32x4){0,0,0,0}, ahl = (f32x4){0,0,0,0}, alh = (f32x4){0,0,0,0};

        // ---- X half: K 0..511, fp32 -> bf16 hi/lo in registers ----
        const float* xp = xrow + (size_t)t * Dd;
#pragma unroll
        for (int ks = 0; ks < 16; ++ks) {
            const int kk = ks * 32 + klo;
            const float4 v0 = *(const float4*)&xp[kk];
            const float4 v1 = *(const float4*)&xp[kk + 4];
            float vv[8] = {v0.x, v0.y, v0.z, v0.w, v1.x, v1.y, v1.z, v1.w};
            bf16x8 ah, al;
#pragma unroll
            for (int e = 0; e < 8; ++e) {
                unsigned short hi = f2bf(vv[e]);
                ah[e] = (short)hi;
                al[e] = (short)f2bf(vv[e] - bf2f(hi));
            }
            const bf16x8 bh = *(const bf16x8*)&bhp[kk];
            const bf16x8 bl = *(const bf16x8*)&blp[kk];
            ahh = __builtin_amdgcn_mfma_f32_16x16x32_bf16(ah, bh, ahh, 0, 0, 0);
            ahl = __builtin_amdgcn_mfma_f32_16x16x32_bf16(ah, bl, ahl, 0, 0, 0);
            alh = __builtin_amdgcn_mfma_f32_16x16x32_bf16(al, bh, alh, 0, 0, 0);
        }
        // ---- h half: K 512..1023, bf16 hi/lo direct ----
#pragma unroll
        for (int ks = 16; ks < 32; ++ks) {
            const int kk = ks * 32 + klo;
            const int kh = kk - 512;
            const bf16x8 ah = *(const bf16x8*)&hrh[hoff + kh];
            const bf16x8 al = *(const bf16x8*)&hrl[hoff + kh];
            const bf16x8 bh = *(const bf16x8*)&bhp[kk];
            const bf16x8 bl = *(const bf16x8*)&blp[kk];
            ahh = __builtin_amdgcn_mfma_f32_16x16x32_bf16(ah, bh, ahh, 0, 0, 0);
            ahl = __builtin_amdgcn_mfma_f32_16x16x32_bf16(ah, bl, ahl, 0, 0, 0);
            alh = __builtin_amdgcn_mfma_f32_16x16x32_bf16(al, bh, alh, 0, 0, 0);
        }

        const f32x4 z = ahh + ahl + alh;
        // C/D layout: col = lane&15, row = (lane>>4)*4 + r
#pragma unroll
        for (int r = 0; r < 4; ++r)
            zbuf[rt * 16 + (lane >> 4) * 4 + r][cw * 16 + l15] = z[r];
        __syncthreads();

        // ---- epilogue: gates + state update (1 elem/thread) ----
        // zbuf col layout: [g0:8][g1:8][g2:8][g3:8] -> gate g at col g*8+ej
        float zi = zbuf[er][0 * 8 + ej] + b0;
        float zf = zbuf[er][1 * 8 + ej] + b1;
        float zg = zbuf[er][2 * 8 + ej] + b2;
        float zo = zbuf[er][3 * 8 + ej] + b3;
        float ig = 1.f / (1.f + expf(-zi));
        float fg = 1.f / (1.f + expf(-zf));
        float gg = tanhf(zg);
        float og = 1.f / (1.f + expf(-zo));
        float cn = fg * creg + ig * gg;
        creg = cn;
        float hn = og * tanhf(cn);
        unsigned short hh = f2bf(hn);
        hwh[oidx] = hh;
        hwl[oidx] = f2bf(hn - bf2f(hh));
        if (t == oT) out[oidx] = hn;

        // ---- group-local barrier (64 WGs), monotonic counter ----
        __threadfence();        // release h writes to device scope
        __syncthreads();        // all threads' writes done before arrival
        if (tid == 0) {
            __hip_atomic_fetch_add(mycnt, 1u, __ATOMIC_ACQ_REL, __HIP_MEMORY_SCOPE_AGENT);
            const unsigned int target = (unsigned int)(t + 1) * GWGS;
            while (__hip_atomic_load(mycnt, __ATOMIC_ACQUIRE, __HIP_MEMORY_SCOPE_AGENT) < target)
                __builtin_amdgcn_s_sleep(8);
        }
        __syncthreads();        // release whole WG; also orders zbuf reuse
        __threadfence();        // acquire-side belt and braces (L1 refresh)
    }
}

// ---------------- Fallback: per-step kernel (round-4 proven path) ----------
__global__ __launch_bounds__(512) void lstm_step4(
    const float* __restrict__ X, const int* __restrict__ lengths,
    const unsigned short* __restrict__ WT_hi, const unsigned short* __restrict__ WT_lo,
    const float* __restrict__ bias,
    float* __restrict__ c_st,
    const unsigned short* __restrict__ h_r_hi, const unsigned short* __restrict__ h_r_lo,
    unsigned short* __restrict__ h_w_hi, unsigned short* __restrict__ h_w_lo,
    float* __restrict__ out, int t)
{
    __shared__ float zbuf[8][16][17];

    const int bx = blockIdx.x;
    const int xcd = bx & 7;
    const int rem = bx >> 3;
    const int m0 = (rem & 15) * 16;
    const int col_group = xcd * 4 + (rem >> 4);
    const int hc0 = col_group * 16;
    const int tid = threadIdx.x;
    const int w8 = tid >> 6;
    const int lane = tid & 63;
    const int gate = w8 & 3;
    const int khalf = w8 >> 2;

    f32x4 ahh = (f32x4){0,0,0,0}, ahl = (f32x4){0,0,0,0}, alh = (f32x4){0,0,0,0};

    const int colk = gate * 512 + hc0 + (lane & 15);
    const size_t bbase = (size_t)colk * KTOT;
    const int klo = (lane >> 4) * 8;
    const int row = m0 + (lane & 15);

    if (khalf == 0) {
        const float* xrow = &X[((size_t)row * Tt + t) * Dd];
        const unsigned short* bhp = &WT_hi[bbase];
        const unsigned short* blp = &WT_lo[bbase];
#pragma unroll
        for (int ks = 0; ks < 16; ++ks) {
            const int kk = ks * 32 + klo;
            const float4 v0 = *(const float4*)&xrow[kk];
            const float4 v1 = *(const float4*)&xrow[kk + 4];
            float vv[8] = {v0.x, v0.y, v0.z, v0.w, v1.x, v1.y, v1.z, v1.w};
            bf16x8 ah, al;
#pragma unroll
            for (int e = 0; e < 8; ++e) {
                unsigned short hi = f2bf(vv[e]);
                ah[e] = (short)hi;
                al[e] = (short)f2bf(vv[e] - bf2f(hi));
            }
            const bf16x8 bh = *(const bf16x8*)&bhp[kk];
            const bf16x8 bl = *(const bf16x8*)&blp[kk];
            ahh = __builtin_amdgcn_mfma_f32_16x16x32_bf16(ah, bh, ahh, 0, 0, 0);
            ahl = __builtin_amdgcn_mfma_f32_16x16x32_bf16(ah, bl, ahl, 0, 0, 0);
            alh = __builtin_amdgcn_mfma_f32_16x16x32_bf16(al, bh, alh, 0, 0, 0);
        }
    } else {
        const unsigned short* hrh = &h_r_hi[(size_t)row * Hh];
        const unsigned short* hrl = &h_r_lo[(size_t)row * Hh];
        const unsigned short* bhp = &WT_hi[bbase + 512];
        const unsigned short* blp = &WT_lo[bbase + 512];
#pragma unroll
        for (int ks = 0; ks < 16; ++ks) {
            const int kk = ks * 32 + klo;
            const bf16x8 ah = *(const bf16x8*)&hrh[kk];
            const bf16x8 al = *(const bf16x8*)&hrl[kk];
            const bf16x8 bh = *(const bf16x8*)&bhp[kk];
            const bf16x8 bl = *(const bf16x8*)&blp[kk];
            ahh = __builtin_amdgcn_mfma_f32_16x16x32_bf16(ah, bh, ahh, 0, 0, 0);
            ahl = __builtin_amdgcn_mfma_f32_16x16x32_bf16(ah, bl, ahl, 0, 0, 0);
            alh = __builtin_amdgcn_mfma_f32_16x16x32_bf16(al, bh, alh, 0, 0, 0);
        }
    }

    const f32x4 z = ahh + ahl + alh;
#pragma unroll
    for (int r = 0; r < 4; ++r)
        zbuf[w8][(lane >> 4) * 4 + r][lane & 15] = z[r];
    __syncthreads();

    if (tid < 256) {
        const int r = tid >> 4;
        const int j = tid & 15;
        const int row_g = m0 + r;
        const int col_g = hc0 + j;
        float zi = zbuf[0][r][j] + zbuf[4][r][j] + bias[col_g];
        float zf = zbuf[1][r][j] + zbuf[5][r][j] + bias[512 + col_g];
        float zg = zbuf[2][r][j] + zbuf[6][r][j] + bias[1024 + col_g];
        float zo = zbuf[3][r][j] + zbuf[7][r][j] + bias[1536 + col_g];
        float ig = 1.f / (1.f + expf(-zi));
        float fg = 1.f / (1.f + expf(-zf));
        float gg = tanhf(zg);
        float og = 1.f / (1.f + expf(-zo));
        const size_t idx = (size_t)row_g * Hh + col_g;
        float cn = fg * c_st[idx] + ig * gg;
        float hn = og * tanhf(cn);
        c_st[idx] = cn;
        unsigned short hh = f2bf(hn);
        h_w_hi[idx] = hh;
        h_w_lo[idx] = f2bf(hn - bf2f(hh));
        int len = lengths[row_g];
        int oidx = len - 1; if (oidx < 0) oidx = 0;
        if (t == oidx) out[idx] = hn;
    }
}

extern "C" void kernel_launch(void* const* d_in, const int* in_sizes, int n_in,
                              void* d_out, int out_size, void* d_ws, size_t ws_size,
                              hipStream_t stream) {
    const float* X = (const float*)d_in[0];
    const int* lengths = (const int*)d_in[1];
    const float* Wx = (const float*)d_in[2];
    const float* Wh = (const float*)d_in[3];
    const float* bias = (const float*)d_in[4];
    float* out = (float*)d_out;

    char* ws = (char*)d_ws;
    unsigned short* WT_hi = (unsigned short*)ws;                               // 4 MB
    unsigned short* WT_lo = (unsigned short*)(ws + (4u << 20));                // 4 MB
    float* c_st = (float*)(ws + (8u << 20));                                   // 512 KB
    unsigned short* h_base = (unsigned short*)(ws + (8u << 20) + (512u << 10)); // 1 MB
    unsigned int* cnt = (unsigned int*)(ws + (8u << 20) + (1536u << 10));      // 1 KB
    const size_t HB = (size_t)Bb * Hh;
    unsigned short* h_hi0 = h_base;
    unsigned short* h_lo0 = h_base + HB;
    unsigned short* h_hi1 = h_base + 2 * HB;
    unsigned short* h_lo1 = h_base + 3 * HB;

    hipLaunchKernelGGL(prep_w, dim3(2048), dim3(256), 0, stream, Wx, Wh, WT_hi, WT_lo);
    hipLaunchKernelGGL(init_state, dim3(512), dim3(256), 0, stream, c_st, h_base, cnt);

    void* args[] = { (void*)&X, (void*)&lengths, (void*)&WT_hi, (void*)&WT_lo,
                     (void*)&bias, (void*)&h_base, (void*)&cnt, (void*)&out };
    hipError_t err = hipLaunchCooperativeKernel((const void*)lstm_persist2,
                                                dim3(256), dim3(512), args, 0, stream);
    if (err != hipSuccess) {
        for (int t = 0; t < Tt; ++t) {
            const bool even = (t & 1) == 0;
            hipLaunchKernelGGL(lstm_step4, dim3(512), dim3(512), 0, stream,
                               X, lengths, WT_hi, WT_lo, bias, c_st,
                               even ? h_hi0 : h_hi1, even ? h_lo0 : h_lo1,
                               even ? h_hi1 : h_hi0, even ? h_lo1 : h_lo0,
                               out, t);
        }
    }
}

// Round 7
// 16253.003 us; speedup vs baseline: 3.5068x; 3.5068x over previous
//
#include <hip/hip_runtime.h>

#define Bb 256
#define Tt 512
#define Dd 512
#define Hh 512
#define KTOT 1024
#define FOURH 2048

typedef __attribute__((ext_vector_type(8))) short bf16x8;
typedef __attribute__((ext_vector_type(4))) float f32x4;

__device__ __forceinline__ unsigned short f2bf(float f) {
    union { float f; unsigned u; } x; x.f = f;
    unsigned u = x.u;
    unsigned r = u + 0x7FFFu + ((u >> 16) & 1u);
    return (unsigned short)(r >> 16);
}
__device__ __forceinline__ float bf2f(unsigned short s) {
    union { unsigned u; float f; } x; x.u = ((unsigned)s) << 16;
    return x.f;
}

// Transpose + split W = [Wx; Wh] (K=1024 rows, N=2048 cols) into
// WT_hi/WT_lo layout [N=2048][K=1024] bf16 (k-contiguous per output column).
__global__ void prep_w(const float* __restrict__ Wx, const float* __restrict__ Wh,
                       unsigned short* __restrict__ WT_hi, unsigned short* __restrict__ WT_lo) {
    __shared__ float tile[32][33];
    int n0 = (blockIdx.x & 63) * 32;
    int k0 = (blockIdx.x >> 6) * 32;
    int tx = threadIdx.x & 31;
    int ty = threadIdx.x >> 5;
    for (int q = 0; q < 4; ++q) {
        int k = k0 + ty + q * 8;
        int n = n0 + tx;
        float v = (k < Dd) ? Wx[(size_t)k * FOURH + n] : Wh[(size_t)(k - Dd) * FOURH + n];
        tile[ty + q * 8][tx] = v;
    }
    __syncthreads();
    for (int q = 0; q < 4; ++q) {
        int nl = ty + q * 8;
        int kl = tx;
        float v = tile[kl][nl];
        unsigned short hi = f2bf(v);
        unsigned short lo = f2bf(v - bf2f(hi));
        size_t o = (size_t)(n0 + nl) * KTOT + (size_t)(k0 + kl);
        WT_hi[o] = hi;
        WT_lo[o] = lo;
    }
}

__global__ void init_state(float* __restrict__ c_st,
                           unsigned short* __restrict__ h_bufs,
                           unsigned int* __restrict__ cnt) {
    int i = blockIdx.x * blockDim.x + threadIdx.x;
    if (i < Bb * Hh) {
        c_st[i] = 0.f;
        for (int q = 0; q < 4; ++q)
            h_bufs[(size_t)q * Bb * Hh + i] = 0;
    }
    if (i < 256) cnt[i] = 0u;
}

// ---------------- Persistent kernel, independent ROW-GROUPS -----------------
// 256 WGs x 512 thr. group = bx>>5 (8 groups x 32 WGs) owns rows 32g..32g+31
// END-TO-END (all 2048 gate-cols). Groups never communicate -> no grid sync.
// WG slot = bx&31 owns h-cols j0=16*slot..+15 (for all 4 gates).
// 8 waves: gate = w8>>1 (0..3), rt = w8&1 (16-row subtile).
// h exchange INSIDE a group: system-scope RELAXED atomics (sc0 sc1 -> served
// at the IF/L3 coherence point; NO L2 flush/invalidate instructions, fully
// placement-independent). Barrier: relaxed system atomic counter + s_sleep
// polling; __syncthreads() drains vmcnt before the signal.
// c in registers; split-3 bf16 MFMA with independent accumulator chains.
__global__ __launch_bounds__(512) void lstm_persist3(
    const float* __restrict__ X, const int* __restrict__ lengths,
    const unsigned short* __restrict__ WT_hi, const unsigned short* __restrict__ WT_lo,
    const float* __restrict__ bias,
    unsigned short* __restrict__ h_base,
    unsigned int* __restrict__ cnt,
    float* __restrict__ out)
{
    __shared__ float zbuf[32][4][17];

    const int bx = blockIdx.x;
    const int group = bx >> 5;          // 0..7
    const int slot = bx & 31;           // 0..31
    const int r0 = group * 32;
    const int j0 = slot * 16;
    const int tid = threadIdx.x;
    const int w8 = tid >> 6;            // 0..7
    const int lane = tid & 63;
    const int l15 = lane & 15;
    const int gate = w8 >> 1;           // 0..3
    const int rt = w8 & 1;              // 0..1

    const size_t HB = (size_t)Bb * Hh;
    unsigned short* h_hi0 = h_base;
    unsigned short* h_lo0 = h_base + HB;
    unsigned short* h_hi1 = h_base + 2 * HB;
    unsigned short* h_lo1 = h_base + 3 * HB;

    // B operand: this lane's gate-column
    const int colg = gate * 512 + j0 + l15;
    const size_t bbase = (size_t)colg * KTOT;
    const unsigned short* bhp = &WT_hi[bbase];
    const unsigned short* blp = &WT_lo[bbase];
    const int klo = (lane >> 4) * 8;    // 0,8,16,24

    // A operand: this lane's row
    const int rowA = r0 + rt * 16 + l15;
    const float* xrow = &X[(size_t)rowA * Tt * Dd];
    const size_t hoff = (size_t)rowA * Hh;

    // epilogue ownership: 1 h-element per thread (32 rows x 16 cols = 512)
    const int er = tid >> 4;            // 0..31
    const int ej = tid & 15;            // 0..15
    const int row_g = r0 + er;
    const int col_h = j0 + ej;
    const size_t oidx = (size_t)row_g * Hh + col_h;
    int oT = lengths[row_g] - 1; if (oT < 0) oT = 0;
    const float b0 = bias[col_h], b1 = bias[512 + col_h],
                b2 = bias[1024 + col_h], b3 = bias[1536 + col_h];
    float creg = 0.f;

    unsigned int* mycnt = &cnt[group * 32];   // 128B-spaced counters

    for (int t = 0; t < Tt; ++t) {
        const unsigned short* hrh = (t & 1) ? h_hi1 : h_hi0;
        const unsigned short* hrl = (t & 1) ? h_lo1 : h_lo0;
        unsigned short* hwh = (t & 1) ? h_hi0 : h_hi1;
        unsigned short* hwl = (t & 1) ? h_lo0 : h_lo1;

        f32x4 ahh = (f32x4){0,0,0,0}, ahl = (f32x4){0,0,0,0}, alh = (f32x4){0,0,0,0};

        // ---- X half: K 0..511, fp32 -> bf16 hi/lo in registers (cached loads)
        const float* xp = xrow + (size_t)t * Dd;
#pragma unroll
        for (int ks = 0; ks < 16; ++ks) {
            const int kk = ks * 32 + klo;
            const float4 v0 = *(const float4*)&xp[kk];
            const float4 v1 = *(const float4*)&xp[kk + 4];
            float vv[8] = {v0.x, v0.y, v0.z, v0.w, v1.x, v1.y, v1.z, v1.w};
            bf16x8 ah, al;
#pragma unroll
            for (int e = 0; e < 8; ++e) {
                unsigned short hi = f2bf(vv[e]);
                ah[e] = (short)hi;
                al[e] = (short)f2bf(vv[e] - bf2f(hi));
            }
            const bf16x8 bh = *(const bf16x8*)&bhp[kk];
            const bf16x8 bl = *(const bf16x8*)&blp[kk];
            ahh = __builtin_amdgcn_mfma_f32_16x16x32_bf16(ah, bh, ahh, 0, 0, 0);
            ahl = __builtin_amdgcn_mfma_f32_16x16x32_bf16(ah, bl, ahl, 0, 0, 0);
            alh = __builtin_amdgcn_mfma_f32_16x16x32_bf16(al, bh, alh, 0, 0, 0);
        }

        // ---- h half: K 512..1023, system-scope relaxed atomic loads (8B x2)
#pragma unroll
        for (int ks = 0; ks < 16; ++ks) {
            const int kh = ks * 32 + klo;
            const unsigned long long* ph = (const unsigned long long*)&hrh[hoff + kh];
            const unsigned long long* pl = (const unsigned long long*)&hrl[hoff + kh];
            union { unsigned long long q[2]; bf16x8 v; } ua, ub;
            ua.q[0] = __hip_atomic_load(ph,     __ATOMIC_RELAXED, __HIP_MEMORY_SCOPE_SYSTEM);
            ua.q[1] = __hip_atomic_load(ph + 1, __ATOMIC_RELAXED, __HIP_MEMORY_SCOPE_SYSTEM);
            ub.q[0] = __hip_atomic_load(pl,     __ATOMIC_RELAXED, __HIP_MEMORY_SCOPE_SYSTEM);
            ub.q[1] = __hip_atomic_load(pl + 1, __ATOMIC_RELAXED, __HIP_MEMORY_SCOPE_SYSTEM);
            const bf16x8 bh = *(const bf16x8*)&bhp[512 + kh];
            const bf16x8 bl = *(const bf16x8*)&blp[512 + kh];
            ahh = __builtin_amdgcn_mfma_f32_16x16x32_bf16(ua.v, bh, ahh, 0, 0, 0);
            ahl = __builtin_amdgcn_mfma_f32_16x16x32_bf16(ua.v, bl, ahl, 0, 0, 0);
            alh = __builtin_amdgcn_mfma_f32_16x16x32_bf16(ub.v, bh, alh, 0, 0, 0);
        }

        const f32x4 z = ahh + ahl + alh;
        // C/D layout: col = lane&15, row = (lane>>4)*4 + r
#pragma unroll
        for (int r = 0; r < 4; ++r)
            zbuf[rt * 16 + (lane >> 4) * 4 + r][gate][l15] = z[r];
        __syncthreads();

        // ---- epilogue: gates + state update (1 elem/thread) ----
        float zi = zbuf[er][0][ej] + b0;
        float zf = zbuf[er][1][ej] + b1;
        float zg = zbuf[er][2][ej] + b2;
        float zo = zbuf[er][3][ej] + b3;
        float ig = 1.f / (1.f + expf(-zi));
        float fg = 1.f / (1.f + expf(-zf));
        float gg = tanhf(zg);
        float og = 1.f / (1.f + expf(-zo));
        float cn = fg * creg + ig * gg;
        creg = cn;
        float hn = og * tanhf(cn);
        unsigned short hh = f2bf(hn);
        unsigned short hl = f2bf(hn - bf2f(hh));
        __hip_atomic_store(&hwh[oidx], hh, __ATOMIC_RELAXED, __HIP_MEMORY_SCOPE_SYSTEM);
        __hip_atomic_store(&hwl[oidx], hl, __ATOMIC_RELAXED, __HIP_MEMORY_SCOPE_SYSTEM);
        if (t == oT) out[oidx] = hn;

        // ---- group-local barrier: relaxed system atomics, NO cache flushes.
        // __syncthreads() drains vmcnt(0) -> h stores are at the coherence
        // point (IF/L3) before the signal add executes there.
        __syncthreads();
        if (tid == 0) {
            __hip_atomic_fetch_add(mycnt, 1u, __ATOMIC_RELAXED, __HIP_MEMORY_SCOPE_SYSTEM);
            const unsigned int target = (unsigned int)(t + 1) * 32u;
            while (__hip_atomic_load(mycnt, __ATOMIC_RELAXED, __HIP_MEMORY_SCOPE_SYSTEM) < target)
                __builtin_amdgcn_s_sleep(2);
        }
        __syncthreads();
    }
}

// ---------------- Fallback: per-step kernel (round-4 proven path) ----------
__global__ __launch_bounds__(512) void lstm_step4(
    const float* __restrict__ X, const int* __restrict__ lengths,
    const unsigned short* __restrict__ WT_hi, const unsigned short* __restrict__ WT_lo,
    const float* __restrict__ bias,
    float* __restrict__ c_st,
    const unsigned short* __restrict__ h_r_hi, const unsigned short* __restrict__ h_r_lo,
    unsigned short* __restrict__ h_w_hi, unsigned short* __restrict__ h_w_lo,
    float* __restrict__ out, int t)
{
    __shared__ float zbuf[8][16][17];

    const int bx = blockIdx.x;
    const int xcd = bx & 7;
    const int rem = bx >> 3;
    const int m0 = (rem & 15) * 16;
    const int col_group = xcd * 4 + (rem >> 4);
    const int hc0 = col_group * 16;
    const int tid = threadIdx.x;
    const int w8 = tid >> 6;
    const int lane = tid & 63;
    const int gate = w8 & 3;
    const int khalf = w8 >> 2;

    f32x4 ahh = (f32x4){0,0,0,0}, ahl = (f32x4){0,0,0,0}, alh = (f32x4){0,0,0,0};

    const int colk = gate * 512 + hc0 + (lane & 15);
    const size_t bbase = (size_t)colk * KTOT;
    const int klo = (lane >> 4) * 8;
    const int row = m0 + (lane & 15);

    if (khalf == 0) {
        const float* xrow = &X[((size_t)row * Tt + t) * Dd];
        const unsigned short* bhp = &WT_hi[bbase];
        const unsigned short* blp = &WT_lo[bbase];
#pragma unroll
        for (int ks = 0; ks < 16; ++ks) {
            const int kk = ks * 32 + klo;
            const float4 v0 = *(const float4*)&xrow[kk];
            const float4 v1 = *(const float4*)&xrow[kk + 4];
            float vv[8] = {v0.x, v0.y, v0.z, v0.w, v1.x, v1.y, v1.z, v1.w};
            bf16x8 ah, al;
#pragma unroll
            for (int e = 0; e < 8; ++e) {
                unsigned short hi = f2bf(vv[e]);
                ah[e] = (short)hi;
                al[e] = (short)f2bf(vv[e] - bf2f(hi));
            }
            const bf16x8 bh = *(const bf16x8*)&bhp[kk];
            const bf16x8 bl = *(const bf16x8*)&blp[kk];
            ahh = __builtin_amdgcn_mfma_f32_16x16x32_bf16(ah, bh, ahh, 0, 0, 0);
            ahl = __builtin_amdgcn_mfma_f32_16x16x32_bf16(ah, bl, ahl, 0, 0, 0);
            alh = __builtin_amdgcn_mfma_f32_16x16x32_bf16(al, bh, alh, 0, 0, 0);
        }
    } else {
        const unsigned short* hrh = &h_r_hi[(size_t)row * Hh];
        const unsigned short* hrl = &h_r_lo[(size_t)row * Hh];
        const unsigned short* bhp = &WT_hi[bbase + 512];
        const unsigned short* blp = &WT_lo[bbase + 512];
#pragma unroll
        for (int ks = 0; ks < 16; ++ks) {
            const int kk = ks * 32 + klo;
            const bf16x8 ah = *(const bf16x8*)&hrh[kk];
            const bf16x8 al = *(const bf16x8*)&hrl[kk];
            const bf16x8 bh = *(const bf16x8*)&bhp[kk];
            const bf16x8 bl = *(const bf16x8*)&blp[kk];
            ahh = __builtin_amdgcn_mfma_f32_16x16x32_bf16(ah, bh, ahh, 0, 0, 0);
            ahl = __builtin_amdgcn_mfma_f32_16x16x32_bf16(ah, bl, ahl, 0, 0, 0);
            alh = __builtin_amdgcn_mfma_f32_16x16x32_bf16(al, bh, alh, 0, 0, 0);
        }
    }

    const f32x4 z = ahh + ahl + alh;
#pragma unroll
    for (int r = 0; r < 4; ++r)
        zbuf[w8][(lane >> 4) * 4 + r][lane & 15] = z[r];
    __syncthreads();

    if (tid < 256) {
        const int r = tid >> 4;
        const int j = tid & 15;
        const int row_g = m0 + r;
        const int col_g = hc0 + j;
        float zi = zbuf[0][r][j] + zbuf[4][r][j] + bias[col_g];
        float zf = zbuf[1][r][j] + zbuf[5][r][j] + bias[512 + col_g];
        float zg = zbuf[2][r][j] + zbuf[6][r][j] + bias[1024 + col_g];
        float zo = zbuf[3][r][j] + zbuf[7][r][j] + bias[1536 + col_g];
        float ig = 1.f / (1.f + expf(-zi));
        float fg = 1.f / (1.f + expf(-zf));
        float gg = tanhf(zg);
        float og = 1.f / (1.f + expf(-zo));
        const size_t idx = (size_t)row_g * Hh + col_g;
        float cn = fg * c_st[idx] + ig * gg;
        float hn = og * tanhf(cn);
        c_st[idx] = cn;
        unsigned short hh = f2bf(hn);
        h_w_hi[idx] = hh;
        h_w_lo[idx] = f2bf(hn - bf2f(hh));
        int len = lengths[row_g];
        int oidx = len - 1; if (oidx < 0) oidx = 0;
        if (t == oidx) out[idx] = hn;
    }
}

extern "C" void kernel_launch(void* const* d_in, const int* in_sizes, int n_in,
                              void* d_out, int out_size, void* d_ws, size_t ws_size,
                              hipStream_t stream) {
    const float* X = (const float*)d_in[0];
    const int* lengths = (const int*)d_in[1];
    const float* Wx = (const float*)d_in[2];
    const float* Wh = (const float*)d_in[3];
    const float* bias = (const float*)d_in[4];
    float* out = (float*)d_out;

    char* ws = (char*)d_ws;
    unsigned short* WT_hi = (unsigned short*)ws;                               // 4 MB
    unsigned short* WT_lo = (unsigned short*)(ws + (4u << 20));                // 4 MB
    float* c_st = (float*)(ws + (8u << 20));                                   // 512 KB
    unsigned short* h_base = (unsigned short*)(ws + (8u << 20) + (512u << 10)); // 1 MB
    unsigned int* cnt = (unsigned int*)(ws + (8u << 20) + (1536u << 10));      // 1 KB
    const size_t HB = (size_t)Bb * Hh;
    unsigned short* h_hi0 = h_base;
    unsigned short* h_lo0 = h_base + HB;
    unsigned short* h_hi1 = h_base + 2 * HB;
    unsigned short* h_lo1 = h_base + 3 * HB;

    hipLaunchKernelGGL(prep_w, dim3(2048), dim3(256), 0, stream, Wx, Wh, WT_hi, WT_lo);
    hipLaunchKernelGGL(init_state, dim3(512), dim3(256), 0, stream, c_st, h_base, cnt);

    void* args[] = { (void*)&X, (void*)&lengths, (void*)&WT_hi, (void*)&WT_lo,
                     (void*)&bias, (void*)&h_base, (void*)&cnt, (void*)&out };
    hipError_t err = hipLaunchCooperativeKernel((const void*)lstm_persist3,
                                                dim3(256), dim3(512), args, 0, stream);
    if (err != hipSuccess) {
        for (int t = 0; t < Tt; ++t) {
            const bool even = (t & 1) == 0;
            hipLaunchKernelGGL(lstm_step4, dim3(512), dim3(512), 0, stream,
                               X, lengths, WT_hi, WT_lo, bias, c_st,
                               even ? h_hi0 : h_hi1, even ? h_lo0 : h_lo1,
                               even ? h_hi1 : h_hi0, even ? h_lo1 : h_lo0,
                               out, t);
        }
    }
}

// Round 8
// 7551.092 us; speedup vs baseline: 7.5481x; 2.1524x over previous
//
#include <hip/hip_runtime.h>

#define Bb 256
#define Tt 512
#define Dd 512
#define Hh 512
#define KTOT 1024
#define FOURH 2048

typedef __attribute__((ext_vector_type(8))) short bf16x8;
typedef __attribute__((ext_vector_type(4))) float f32x4;

__device__ __forceinline__ unsigned short f2bf(float f) {
    union { float f; unsigned u; } x; x.f = f;
    unsigned u = x.u;
    unsigned r = u + 0x7FFFu + ((u >> 16) & 1u);
    return (unsigned short)(r >> 16);
}
__device__ __forceinline__ float bf2f(unsigned short s) {
    union { unsigned u; float f; } x; x.u = ((unsigned)s) << 16;
    return x.f;
}

__device__ __forceinline__ uint4 load16_sc0(const void* p) {
    uint4 v;
    asm volatile("global_load_dwordx4 %0, %1, off sc0" : "=v"(v) : "v"(p));
    return v;
}
__device__ __forceinline__ uint4 load16_sc01(const void* p) {
    uint4 v;
    asm volatile("global_load_dwordx4 %0, %1, off sc0 sc1" : "=v"(v) : "v"(p));
    return v;
}

// Transpose + split W = [Wx; Wh] into WT_hi/WT_lo [N=2048][K=1024] bf16.
__global__ void prep_w(const float* __restrict__ Wx, const float* __restrict__ Wh,
                       unsigned short* __restrict__ WT_hi, unsigned short* __restrict__ WT_lo) {
    __shared__ float tile[32][33];
    int n0 = (blockIdx.x & 63) * 32;
    int k0 = (blockIdx.x >> 6) * 32;
    int tx = threadIdx.x & 31;
    int ty = threadIdx.x >> 5;
    for (int q = 0; q < 4; ++q) {
        int k = k0 + ty + q * 8;
        int n = n0 + tx;
        float v = (k < Dd) ? Wx[(size_t)k * FOURH + n] : Wh[(size_t)(k - Dd) * FOURH + n];
        tile[ty + q * 8][tx] = v;
    }
    __syncthreads();
    for (int q = 0; q < 4; ++q) {
        int nl = ty + q * 8;
        int kl = tx;
        float v = tile[kl][nl];
        unsigned short hi = f2bf(v);
        unsigned short lo = f2bf(v - bf2f(hi));
        size_t o = (size_t)(n0 + nl) * KTOT + (size_t)(k0 + kl);
        WT_hi[o] = hi;
        WT_lo[o] = lo;
    }
}

// ctrl: [0..255] per-group barrier counters (group*32), [256..263] claim pools,
//       [264] rendezvous counter.
__global__ void init_state(float* __restrict__ c_st,
                           unsigned short* __restrict__ h_bufs,
                           unsigned int* __restrict__ ctrl) {
    int i = blockIdx.x * blockDim.x + threadIdx.x;
    if (i < Bb * Hh) {
        c_st[i] = 0.f;
        for (int q = 0; q < 4; ++q)
            h_bufs[(size_t)q * Bb * Hh + i] = 0;
    }
    if (i < 272) ctrl[i] = 0u;
}

// ---------------- Persistent kernel, XCD-LOCAL row groups -------------------
// 256 WGs x 512 thr (1 WG/CU). Work claimed by PHYSICAL XCD (HW_REG_XCC_ID):
// group g (32 WGs, all on XCD g when placement is clean) owns rows 32g..32g+31
// end-to-end; slot owns 16 h-cols (x4 gates = 64 gate-cols).
// h exchange: clean group -> plain stores + sc0 loads (home-L2 coherent);
// mixed group (fallback, any placement) -> MALL path (sc0 sc1), R7-proven.
// Per step: stage h(64KB,sc0)+X(64KB fp32->hi/lo) into LDS once per WG; waves
// (gate, khalf) read A from LDS (linear, conflict-free), B (W) from global.
// Barrier: per-group relaxed system counter, no fences, no cache flushes.
__global__ __launch_bounds__(512) void lstm_persist5(
    const float* __restrict__ X, const int* __restrict__ lengths,
    const unsigned short* __restrict__ WT_hi, const unsigned short* __restrict__ WT_lo,
    const float* __restrict__ bias,
    unsigned short* __restrict__ h_base,
    unsigned int* __restrict__ ctrl,
    float* __restrict__ out)
{
    __shared__ unsigned short HLDS[32768];   // 64 KB: h hi/lo staged
    __shared__ unsigned short XLDS[32768];   // 64 KB: x hi/lo staged
    __shared__ float zbuf[8][32][17];        // 17 KB
    __shared__ int sgrp, sslt, smix;

    const int tid = threadIdx.x;
    const int w8 = tid >> 6;
    const int lane = tid & 63;
    const int l15 = lane & 15;
    const int q4 = lane >> 4;            // 0..3
    const int klo = q4 * 8;

    unsigned xcc;
    asm volatile("s_getreg_b32 %0, hwreg(HW_REG_XCC_ID, 0, 4)" : "=s"(xcc));
    xcc &= 7u;

    unsigned int* pool = ctrl + 256;
    unsigned int* rcnt = ctrl + 264;

    // ---- one-time claim + rendezvous + overflow resolution ----
    if (tid == 0) {
        unsigned my = __hip_atomic_fetch_add(&pool[xcc], 1u, __ATOMIC_RELAXED, __HIP_MEMORY_SCOPE_SYSTEM);
        asm volatile("s_waitcnt vmcnt(0)" ::: "memory");
        __hip_atomic_fetch_add(rcnt, 1u, __ATOMIC_RELAXED, __HIP_MEMORY_SCOPE_SYSTEM);
        while (__hip_atomic_load(rcnt, __ATOMIC_RELAXED, __HIP_MEMORY_SCOPE_SYSTEM) < 256u)
            __builtin_amdgcn_s_sleep(2);
        unsigned cl[8];
        for (int g = 0; g < 8; ++g)
            cl[g] = __hip_atomic_load(&pool[g], __ATOMIC_RELAXED, __HIP_MEMORY_SCOPE_SYSTEM);
        int group = 0, slot = 0;
        if (my < 32u) { group = (int)xcc; slot = (int)my; }
        else {
            int r = (int)my - 32;
            for (int g = 0; g < (int)xcc; ++g) { int e = (int)cl[g] - 32; if (e > 0) r += e; }
            for (int g = 0; g < 8; ++g) {
                int def = 32 - (int)cl[g];
                if (def <= 0) continue;
                if (r < def) { group = g; slot = (int)cl[g] + r; break; }
                r -= def;
            }
        }
        sgrp = group; sslt = slot; smix = (cl[group] < 32u) ? 1 : 0;
    }
    __syncthreads();
    const int group = sgrp;
    const int slot = sslt;
    const int mixed = smix;

    const int r0 = group * 32;
    const int j0 = slot * 16;
    const int gate = w8 & 3;
    const int khalf = w8 >> 2;

    const size_t HB = (size_t)Bb * Hh;
    unsigned short* h_hi0 = h_base;
    unsigned short* h_lo0 = h_base + HB;
    unsigned short* h_hi1 = h_base + 2 * HB;
    unsigned short* h_lo1 = h_base + 3 * HB;

    // B operand: this lane's gate-column
    const int colg = gate * 512 + j0 + l15;
    const size_t bbase = (size_t)colg * KTOT + (size_t)khalf * 512;
    const unsigned short* bhp = &WT_hi[bbase];
    const unsigned short* blp = &WT_lo[bbase];

    // X staging: thread stages row xr (0..31), k xk0..xk0+31
    const int xr = tid >> 4;
    const int xk0 = (tid & 15) * 32;
    const float* xbase = &X[((size_t)(r0 + xr) * Tt) * Dd + xk0];

    // epilogue ownership: 1 h-element per thread (32 rows x 16 cols)
    const int er = tid >> 4;
    const int ej = tid & 15;
    const int row_g = r0 + er;
    const int col_h = j0 + ej;
    const size_t oidx = (size_t)row_g * Hh + col_h;
    int oT = lengths[row_g] - 1; if (oT < 0) oT = 0;
    const float b0 = bias[col_h], b1 = bias[512 + col_h],
                b2 = bias[1024 + col_h], b3 = bias[1536 + col_h];
    float creg = 0.f;

    unsigned int* mycnt = &ctrl[group * 32];

    for (int t = 0; t < Tt; ++t) {
        const unsigned short* hrh = (t & 1) ? h_hi1 : h_hi0;
        const unsigned short* hrl = (t & 1) ? h_lo1 : h_lo0;
        unsigned short* hwh = (t & 1) ? h_hi0 : h_hi1;
        unsigned short* hwl = (t & 1) ? h_lo0 : h_lo1;

        // ================= stage phase =================
        // X: 8 float4 per thread (plain cached loads)
        float4 xv[8];
        const float* xp = xbase + (size_t)t * Dd;
#pragma unroll
        for (int i = 0; i < 8; ++i) xv[i] = ((const float4*)xp)[i];

        // h: 8x16B per thread, L1-bypassing loads (sc0 clean / sc0 sc1 mixed)
        uint4 hv[8];
        const unsigned short* hsliceh = hrh + (size_t)r0 * Hh;
        const unsigned short* hslicel = hrl + (size_t)r0 * Hh;
        if (!mixed) {
#pragma unroll
            for (int i = 0; i < 8; ++i) {
                const int c = i * 512 + tid;
                const unsigned short* src = ((c >> 11) ? hslicel : hsliceh) + (c & 2047) * 8;
                hv[i] = load16_sc0(src);
            }
        } else {
#pragma unroll
            for (int i = 0; i < 8; ++i) {
                const int c = i * 512 + tid;
                const unsigned short* src = ((c >> 11) ? hslicel : hsliceh) + (c & 2047) * 8;
                hv[i] = load16_sc01(src);
            }
        }
        asm volatile("s_waitcnt vmcnt(0)" ::: "memory");
        __builtin_amdgcn_sched_barrier(0);

        // write h chunks to HLDS: [arr][mi][ks][lane] 16B
#pragma unroll
        for (int i = 0; i < 8; ++i) {
            const int c = i * 512 + tid;
            const int arr = c >> 11, cc = c & 2047;
            const int row = cc >> 6, k8 = cc & 63;
            const int mi = row >> 4, lr = row & 15, ks = k8 >> 2, qq = k8 & 3;
            *(uint4*)&HLDS[((size_t)((arr * 2 + mi) * 16 + ks) * 64 + (qq * 16 + lr)) * 8] = hv[i];
        }
        // convert + write X chunks to XLDS (same layout)
#pragma unroll
        for (int c2 = 0; c2 < 4; ++c2) {
            float vv[8];
            *(float4*)&vv[0] = xv[2 * c2];
            *(float4*)&vv[4] = xv[2 * c2 + 1];
            bf16x8 hv8, lv8;
#pragma unroll
            for (int e = 0; e < 8; ++e) {
                unsigned short hs = f2bf(vv[e]);
                hv8[e] = (short)hs;
                lv8[e] = (short)f2bf(vv[e] - bf2f(hs));
            }
            const int k = xk0 + c2 * 8;
            const int mi = xr >> 4, lr = xr & 15, ks = k >> 5, qq = (k >> 3) & 3;
            const int lidx = ((mi * 16 + ks) * 64 + (qq * 16 + lr)) * 8;
            *(bf16x8*)&XLDS[lidx] = hv8;
            *(bf16x8*)&XLDS[lidx + 16384] = lv8;
        }
        __syncthreads();

        // ================= compute phase =================
        const unsigned short* ALDS = khalf ? HLDS : XLDS;
        f32x4 acc[2][3];
#pragma unroll
        for (int mi = 0; mi < 2; ++mi)
#pragma unroll
            for (int s = 0; s < 3; ++s)
                acc[mi][s] = (f32x4){0.f, 0.f, 0.f, 0.f};

#pragma unroll
        for (int ks = 0; ks < 16; ++ks) {
            const int kk = ks * 32 + klo;
            const bf16x8 bh = *(const bf16x8*)&bhp[kk];
            const bf16x8 bl = *(const bf16x8*)&blp[kk];
#pragma unroll
            for (int mi = 0; mi < 2; ++mi) {
                const bf16x8 ah = *(const bf16x8*)&ALDS[((mi * 16 + ks) * 64 + lane) * 8];
                const bf16x8 al = *(const bf16x8*)&ALDS[(((2 + mi) * 16 + ks) * 64 + lane) * 8];
                acc[mi][0] = __builtin_amdgcn_mfma_f32_16x16x32_bf16(ah, bh, acc[mi][0], 0, 0, 0);
                acc[mi][1] = __builtin_amdgcn_mfma_f32_16x16x32_bf16(ah, bl, acc[mi][1], 0, 0, 0);
                acc[mi][2] = __builtin_amdgcn_mfma_f32_16x16x32_bf16(al, bh, acc[mi][2], 0, 0, 0);
            }
        }

        // z tiles -> LDS (C/D: col=lane&15, row=(lane>>4)*4+r)
#pragma unroll
        for (int mi = 0; mi < 2; ++mi) {
            const f32x4 z = acc[mi][0] + acc[mi][1] + acc[mi][2];
#pragma unroll
            for (int r = 0; r < 4; ++r)
                zbuf[w8][mi * 16 + q4 * 4 + r][l15] = z[r];
        }
        __syncthreads();

        // ================= epilogue =================
        float zi = zbuf[0][er][ej] + zbuf[4][er][ej] + b0;
        float zf = zbuf[1][er][ej] + zbuf[5][er][ej] + b1;
        float zg = zbuf[2][er][ej] + zbuf[6][er][ej] + b2;
        float zo = zbuf[3][er][ej] + zbuf[7][er][ej] + b3;
        float ig = 1.f / (1.f + expf(-zi));
        float fg = 1.f / (1.f + expf(-zf));
        float gg = tanhf(zg);
        float og = 1.f / (1.f + expf(-zo));
        float cn = fg * creg + ig * gg;
        creg = cn;
        float hn = og * tanhf(cn);
        unsigned short hh = f2bf(hn);
        unsigned short hl = f2bf(hn - bf2f(hh));
        if (!mixed) {
            hwh[oidx] = hh;
            hwl[oidx] = hl;
        } else {
            __hip_atomic_store(&hwh[oidx], hh, __ATOMIC_RELAXED, __HIP_MEMORY_SCOPE_SYSTEM);
            __hip_atomic_store(&hwl[oidx], hl, __ATOMIC_RELAXED, __HIP_MEMORY_SCOPE_SYSTEM);
        }
        if (t == oT) out[oidx] = hn;

        // ---- group barrier: 32 arrivals, relaxed, no cache maintenance ----
        if (t < Tt - 1) {
            __syncthreads();   // drains vmcnt: h stores visible at L2/MALL
            if (tid == 0) {
                __hip_atomic_fetch_add(mycnt, 1u, __ATOMIC_RELAXED, __HIP_MEMORY_SCOPE_SYSTEM);
                const unsigned int target = (unsigned int)(t + 1) * 32u;
                while (__hip_atomic_load(mycnt, __ATOMIC_RELAXED, __HIP_MEMORY_SCOPE_SYSTEM) < target)
                    __builtin_amdgcn_s_sleep(2);
            }
            __syncthreads();
        }
    }
}

// ---------------- Fallback: per-step kernel (round-4 proven path) ----------
__global__ __launch_bounds__(512) void lstm_step4(
    const float* __restrict__ X, const int* __restrict__ lengths,
    const unsigned short* __restrict__ WT_hi, const unsigned short* __restrict__ WT_lo,
    const float* __restrict__ bias,
    float* __restrict__ c_st,
    const unsigned short* __restrict__ h_r_hi, const unsigned short* __restrict__ h_r_lo,
    unsigned short* __restrict__ h_w_hi, unsigned short* __restrict__ h_w_lo,
    float* __restrict__ out, int t)
{
    __shared__ float zbuf[8][16][17];

    const int bx = blockIdx.x;
    const int xcd = bx & 7;
    const int rem = bx >> 3;
    const int m0 = (rem & 15) * 16;
    const int col_group = xcd * 4 + (rem >> 4);
    const int hc0 = col_group * 16;
    const int tid = threadIdx.x;
    const int w8 = tid >> 6;
    const int lane = tid & 63;
    const int gate = w8 & 3;
    const int khalf = w8 >> 2;

    f32x4 ahh = (f32x4){0,0,0,0}, ahl = (f32x4){0,0,0,0}, alh = (f32x4){0,0,0,0};

    const int colk = gate * 512 + hc0 + (lane & 15);
    const size_t bbase = (size_t)colk * KTOT;
    const int klo = (lane >> 4) * 8;
    const int row = m0 + (lane & 15);

    if (khalf == 0) {
        const float* xrow = &X[((size_t)row * Tt + t) * Dd];
        const unsigned short* bhp = &WT_hi[bbase];
        const unsigned short* blp = &WT_lo[bbase];
#pragma unroll
        for (int ks = 0; ks < 16; ++ks) {
            const int kk = ks * 32 + klo;
            const float4 v0 = *(const float4*)&xrow[kk];
            const float4 v1 = *(const float4*)&xrow[kk + 4];
            float vv[8] = {v0.x, v0.y, v0.z, v0.w, v1.x, v1.y, v1.z, v1.w};
            bf16x8 ah, al;
#pragma unroll
            for (int e = 0; e < 8; ++e) {
                unsigned short hi = f2bf(vv[e]);
                ah[e] = (short)hi;
                al[e] = (short)f2bf(vv[e] - bf2f(hi));
            }
            const bf16x8 bh = *(const bf16x8*)&bhp[kk];
            const bf16x8 bl = *(const bf16x8*)&blp[kk];
            ahh = __builtin_amdgcn_mfma_f32_16x16x32_bf16(ah, bh, ahh, 0, 0, 0);
            ahl = __builtin_amdgcn_mfma_f32_16x16x32_bf16(ah, bl, ahl, 0, 0, 0);
            alh = __builtin_amdgcn_mfma_f32_16x16x32_bf16(al, bh, alh, 0, 0, 0);
        }
    } else {
        const unsigned short* hrh = &h_r_hi[(size_t)row * Hh];
        const unsigned short* hrl = &h_r_lo[(size_t)row * Hh];
        const unsigned short* bhp = &WT_hi[bbase + 512];
        const unsigned short* blp = &WT_lo[bbase + 512];
#pragma unroll
        for (int ks = 0; ks < 16; ++ks) {
            const int kk = ks * 32 + klo;
            const bf16x8 ah = *(const bf16x8*)&hrh[kk];
            const bf16x8 al = *(const bf16x8*)&hrl[kk];
            const bf16x8 bh = *(const bf16x8*)&bhp[kk];
            const bf16x8 bl = *(const bf16x8*)&blp[kk];
            ahh = __builtin_amdgcn_mfma_f32_16x16x32_bf16(ah, bh, ahh, 0, 0, 0);
            ahl = __builtin_amdgcn_mfma_f32_16x16x32_bf16(ah, bl, ahl, 0, 0, 0);
            alh = __builtin_amdgcn_mfma_f32_16x16x32_bf16(al, bh, alh, 0, 0, 0);
        }
    }

    const f32x4 z = ahh + ahl + alh;
#pragma unroll
    for (int r = 0; r < 4; ++r)
        zbuf[w8][(lane >> 4) * 4 + r][lane & 15] = z[r];
    __syncthreads();

    if (tid < 256) {
        const int r = tid >> 4;
        const int j = tid & 15;
        const int row_g = m0 + r;
        const int col_g = hc0 + j;
        float zi = zbuf[0][r][j] + zbuf[4][r][j] + bias[col_g];
        float zf = zbuf[1][r][j] + zbuf[5][r][j] + bias[512 + col_g];
        float zg = zbuf[2][r][j] + zbuf[6][r][j] + bias[1024 + col_g];
        float zo = zbuf[3][r][j] + zbuf[7][r][j] + bias[1536 + col_g];
        float ig = 1.f / (1.f + expf(-zi));
        float fg = 1.f / (1.f + expf(-zf));
        float gg = tanhf(zg);
        float og = 1.f / (1.f + expf(-zo));
        const size_t idx = (size_t)row_g * Hh + col_g;
        float cn = fg * c_st[idx] + ig * gg;
        float hn = og * tanhf(cn);
        c_st[idx] = cn;
        unsigned short hh = f2bf(hn);
        h_w_hi[idx] = hh;
        h_w_lo[idx] = f2bf(hn - bf2f(hh));
        int len = lengths[row_g];
        int oidx = len - 1; if (oidx < 0) oidx = 0;
        if (t == oidx) out[idx] = hn;
    }
}

extern "C" void kernel_launch(void* const* d_in, const int* in_sizes, int n_in,
                              void* d_out, int out_size, void* d_ws, size_t ws_size,
                              hipStream_t stream) {
    const float* X = (const float*)d_in[0];
    const int* lengths = (const int*)d_in[1];
    const float* Wx = (const float*)d_in[2];
    const float* Wh = (const float*)d_in[3];
    const float* bias = (const float*)d_in[4];
    float* out = (float*)d_out;

    char* ws = (char*)d_ws;
    unsigned short* WT_hi = (unsigned short*)ws;                               // 4 MB
    unsigned short* WT_lo = (unsigned short*)(ws + (4u << 20));                // 4 MB
    float* c_st = (float*)(ws + (8u << 20));                                   // 512 KB
    unsigned short* h_base = (unsigned short*)(ws + (8u << 20) + (512u << 10)); // 1 MB
    unsigned int* ctrl = (unsigned int*)(ws + (8u << 20) + (1536u << 10));     // ~1.1 KB
    const size_t HB = (size_t)Bb * Hh;
    unsigned short* h_hi0 = h_base;
    unsigned short* h_lo0 = h_base + HB;
    unsigned short* h_hi1 = h_base + 2 * HB;
    unsigned short* h_lo1 = h_base + 3 * HB;

    hipLaunchKernelGGL(prep_w, dim3(2048), dim3(256), 0, stream, Wx, Wh, WT_hi, WT_lo);
    hipLaunchKernelGGL(init_state, dim3(512), dim3(256), 0, stream, c_st, h_base, ctrl);

    void* args[] = { (void*)&X, (void*)&lengths, (void*)&WT_hi, (void*)&WT_lo,
                     (void*)&bias, (void*)&h_base, (void*)&ctrl, (void*)&out };
    hipError_t err = hipLaunchCooperativeKernel((const void*)lstm_persist5,
                                                dim3(256), dim3(512), args, 0, stream);
    if (err != hipSuccess) {
        for (int t = 0; t < Tt; ++t) {
            const bool even = (t & 1) == 0;
            hipLaunchKernelGGL(lstm_step4, dim3(512), dim3(512), 0, stream,
                               X, lengths, WT_hi, WT_lo, bias, c_st,
                               even ? h_hi0 : h_hi1, even ? h_lo0 : h_lo1,
                               even ? h_hi1 : h_hi0, even ? h_lo1 : h_lo0,
                               out, t);
        }
    }
}